// Round 1
// baseline (827.846 us; speedup 1.0000x reference)
//
#include <hip/hip_runtime.h>
#include <stdint.h>

#define D_MODEL 1024
#define T_SEQ   2048
#define N_BATCH 4
#define M_ROWS  (N_BATCH*T_SEQ)   // 8192
#define N_STATE 16

typedef float  f32x4  __attribute__((ext_vector_type(4)));
typedef __bf16 bf16x8 __attribute__((ext_vector_type(8)));
typedef __bf16 bf16x4 __attribute__((ext_vector_type(4)));

__device__ __forceinline__ void gload16(const void* g, void* l) {
  __builtin_amdgcn_global_load_lds(
      (const __attribute__((address_space(1))) uint32_t*)g,
      (__attribute__((address_space(3))) uint32_t*)l, 16, 0, 0);
}

__device__ __forceinline__ float sigmoidf_(float v){ return 1.f/(1.f+__expf(-v)); }

// ---------------- cast fp32 -> bf16 ----------------
__global__ __launch_bounds__(256) void cast_bf16_kernel(const float* __restrict__ in,
                                                        __bf16* __restrict__ out, int n4){
  int i = blockIdx.x*256 + threadIdx.x;
  if (i >= n4) return;
  float4 v = ((const float4*)in)[i];
  bf16x4 o; o[0]=(__bf16)v.x; o[1]=(__bf16)v.y; o[2]=(__bf16)v.z; o[3]=(__bf16)v.w;
  ((bf16x4*)out)[i] = o;
}

// ---------------- transpose + cast: W (K x N) fp32 -> out (N x K) bf16 ----------------
__global__ __launch_bounds__(256) void transpose_cast_kernel(const float* __restrict__ W,
                                                             __bf16* __restrict__ out,
                                                             int K, int N){
  __shared__ float tile[32][33];
  const int tx = threadIdx.x, ty = threadIdx.y;
  const int n0 = blockIdx.x*32, k0 = blockIdx.y*32;
  #pragma unroll
  for (int i=0;i<4;i++)
    tile[ty+i*8][tx] = W[(size_t)(k0+ty+i*8)*N + n0+tx];
  __syncthreads();
  #pragma unroll
  for (int i=0;i<4;i++)
    out[(size_t)(n0+ty+i*8)*K + k0+tx] = (__bf16)tile[tx][ty+i*8];
}

// ---------------- MFMA GEMM: C = A(MxK) * Bt(NxK)^T, m97-style 128x128 tile ----------------
#define BM 128
#define BN 128
#define BK 32

// EPI 0: proj -> out0=x_ssm (col<1024), out1=silu(gate) (col>=1024)
// EPI 1: dt/BC -> out0=softplus(v+b_dt) (col<1024), out1=BC raw (stride 32)
// EPI 2: out0 = v + bias0 + addx  (residual pre-LN)
template<int EPI>
__global__ __launch_bounds__(256)
void gemm_bt(const __bf16* __restrict__ A, const __bf16* __restrict__ Bt,
             int N, int K,
             const float* __restrict__ bias0, const float* __restrict__ bias1,
             float* __restrict__ out0, float* __restrict__ out1,
             const float* __restrict__ addx)
{
  __shared__ __align__(16) __bf16 As[BM*BK];
  __shared__ __align__(16) __bf16 Bs[BN*BK];
  const int tid = threadIdx.x, wave = tid>>6, lane = tid&63;
  const int m0 = blockIdx.y*BM, n0 = blockIdx.x*BN;
  const int wr = wave>>1, wc = wave&1;

  f32x4 acc[4][4];
  #pragma unroll
  for (int a=0;a<4;a++)
    #pragma unroll
    for (int b=0;b<4;b++) acc[a][b] = (f32x4){0.f,0.f,0.f,0.f};

  // staging chunk ids: 512 16B-chunks per 8KB tile; 2 per thread
  const int c0 = wave*128 + lane, c1 = c0 + 64;
  const int r0 = c0>>2, s0 = (c0&3)*8;
  const int r1 = c1>>2, s1 = (c1&3)*8;
  const int arow = wr*64 + (lane&15), brow = wc*64 + (lane&15);
  const int kg = (lane>>4)*8;

  for (int kk=0; kk<K; kk+=BK) {
    gload16(&A [(size_t)(m0+r0)*K + kk + s0], &As[c0*8]);
    gload16(&A [(size_t)(m0+r1)*K + kk + s1], &As[c1*8]);
    gload16(&Bt[(size_t)(n0+r0)*K + kk + s0], &Bs[c0*8]);
    gload16(&Bt[(size_t)(n0+r1)*K + kk + s1], &Bs[c1*8]);
    __syncthreads();   // drains vmcnt (compiler-inserted) -> tiles ready
    bf16x8 af[4], bfv[4];
    #pragma unroll
    for (int m=0;m<4;m++) af[m]  = *(const bf16x8*)&As[(arow+m*16)*BK + kg];
    #pragma unroll
    for (int n=0;n<4;n++) bfv[n] = *(const bf16x8*)&Bs[(brow+n*16)*BK + kg];
    #pragma unroll
    for (int m=0;m<4;m++)
      #pragma unroll
      for (int n=0;n<4;n++)
        acc[m][n] = __builtin_amdgcn_mfma_f32_16x16x32_bf16(af[m], bfv[n], acc[m][n], 0,0,0);
    __syncthreads();
  }

  const int cr = (lane>>4)*4, cc = lane&15;
  #pragma unroll
  for (int m=0;m<4;m++){
    const int row = m0 + wr*64 + m*16 + cr;
    #pragma unroll
    for (int n=0;n<4;n++){
      const int col = n0 + wc*64 + n*16 + cc;
      if (col >= N) continue;
      #pragma unroll
      for (int r=0;r<4;r++){
        float v = acc[m][n][r];
        const size_t ri = (size_t)(row + r);
        if constexpr (EPI==0){
          v += bias0[col];
          if (col < D_MODEL) out0[ri*D_MODEL + col] = v;
          else               out1[ri*D_MODEL + (col-D_MODEL)] = v * sigmoidf_(v);
        } else if constexpr (EPI==1){
          if (col < D_MODEL){
            v += bias0[col];
            out0[ri*D_MODEL + col] = (v > 20.f) ? v : log1pf(__expf(v));
          } else {
            v += bias1[col-D_MODEL];
            out1[ri*32 + (col-D_MODEL)] = v;
          }
        } else {
          v += bias0[col] + addx[ri*D_MODEL + col];
          out0[ri*D_MODEL + col] = v;
        }
      }
    }
  }
}

// ---------------- causal depthwise conv(4) + silu; writes fp32 + bf16 copies ----------------
__global__ __launch_bounds__(256) void conv_silu_kernel(
    const float* __restrict__ xssm, const float* __restrict__ cw, const float* __restrict__ cb,
    float* __restrict__ xcf, __bf16* __restrict__ xcb)
{
  const int bt = blockIdx.x;            // b*T + t
  const int t  = bt & (T_SEQ-1);
  const int d  = threadIdx.x*4;
  float4 w[4];
  #pragma unroll
  for (int j=0;j<4;j++) w[j] = *(const float4*)&cw[(d+j)*4];
  float4 acc = *(const float4*)&cb[d];
  #pragma unroll
  for (int k=0;k<4;k++){
    const int tt = t-3+k;
    if (tt >= 0){
      float4 xv = *(const float4*)&xssm[(size_t)(bt-3+k)*D_MODEL + d];
      acc.x = fmaf(xv.x, ((const float*)&w[0])[k], acc.x);
      acc.y = fmaf(xv.y, ((const float*)&w[1])[k], acc.y);
      acc.z = fmaf(xv.z, ((const float*)&w[2])[k], acc.z);
      acc.w = fmaf(xv.w, ((const float*)&w[3])[k], acc.w);
    }
  }
  acc.x *= sigmoidf_(acc.x); acc.y *= sigmoidf_(acc.y);
  acc.z *= sigmoidf_(acc.z); acc.w *= sigmoidf_(acc.w);
  *(float4*)&xcf[(size_t)bt*D_MODEL + d] = acc;
  bf16x4 o; o[0]=(__bf16)acc.x; o[1]=(__bf16)acc.y; o[2]=(__bf16)acc.z; o[3]=(__bf16)acc.w;
  ((bf16x4*)xcb)[((size_t)bt*D_MODEL + d)>>2] = o;
}

// ---------------- selective scan: block = (b, 16 d-channels); lane=(d-sub, n) ----------------
__global__ __launch_bounds__(256) void scan_kernel(
    const float* __restrict__ xcf, const float* __restrict__ dtb, const float* __restrict__ BC,
    const float* __restrict__ A_log, const float* __restrict__ Dvec,
    const float* __restrict__ gsil, __bf16* __restrict__ ybf)
{
  const int dg = blockIdx.x;            // 0..63
  const int b  = blockIdx.y;            // 0..3
  const int d0 = dg*16;
  const int tid = threadIdx.x, wave = tid>>6, lane = tid&63;
  const int n = lane & 15, dl = wave*4 + (lane>>4);   // dl in 0..15
  const int d = d0 + dl;
  const float a_dn = -__expf(A_log[(size_t)d*N_STATE + n]);
  const float Dd = Dvec[d];
  __shared__ float s_dt[16][16], s_xc[16][16], s_B[16][16], s_C[16][16], s_y[16][16];
  float h = 0.f;
  const int lt = tid>>4, ldd = tid&15;  // cooperative load coords
  const size_t baseM = (size_t)b*T_SEQ;

  for (int tc=0; tc<T_SEQ; tc+=16){
    const size_t row = baseM + tc + lt;
    s_dt[lt][ldd] = dtb[row*D_MODEL + d0 + ldd];
    s_xc[lt][ldd] = xcf[row*D_MODEL + d0 + ldd];
    s_B [lt][ldd] = BC[row*32 + ldd];
    s_C [lt][ldd] = BC[row*32 + 16 + ldd];
    __syncthreads();
    #pragma unroll
    for (int t=0;t<16;t++){
      const float dtv = s_dt[t][dl], xcv = s_xc[t][dl];
      const float bv = s_B[t][n], cv = s_C[t][n];
      const float dA = __expf(dtv * a_dn);
      h = fmaf(h, dA, dtv*xcv*bv);
      float py = h * cv;
      py += __shfl_xor(py,1); py += __shfl_xor(py,2);
      py += __shfl_xor(py,4); py += __shfl_xor(py,8);
      if (n==0) s_y[t][dl] = fmaf(Dd, xcv, py);
    }
    __syncthreads();
    const float yv = s_y[lt][ldd] * gsil[row*D_MODEL + d0 + ldd];
    ybf[row*D_MODEL + d0 + ldd] = (__bf16)yv;
  }
}

// ---------------- layernorm, in place on d_out ----------------
__global__ __launch_bounds__(256) void ln_kernel(float* __restrict__ io,
    const float* __restrict__ g, const float* __restrict__ b)
{
  const int row = blockIdx.x, tid = threadIdx.x;
  float4* p = (float4*)(io + (size_t)row*D_MODEL);
  float4 v = p[tid];
  float s  = v.x+v.y+v.z+v.w;
  float s2 = v.x*v.x + v.y*v.y + v.z*v.z + v.w*v.w;
  #pragma unroll
  for (int o=1;o<64;o<<=1){ s += __shfl_xor(s,o); s2 += __shfl_xor(s2,o); }
  __shared__ float red[8];
  const int wave = tid>>6, lane = tid&63;
  if (lane==0){ red[wave]=s; red[4+wave]=s2; }
  __syncthreads();
  s  = red[0]+red[1]+red[2]+red[3];
  s2 = red[4]+red[5]+red[6]+red[7];
  const float mu  = s*(1.f/D_MODEL);
  const float var = s2*(1.f/D_MODEL) - mu*mu;
  const float rs  = rsqrtf(var + 1e-5f);
  float4 gg = ((const float4*)g)[tid], bb = ((const float4*)b)[tid];
  float4 o;
  o.x = (v.x-mu)*rs*gg.x + bb.x;
  o.y = (v.y-mu)*rs*gg.y + bb.y;
  o.z = (v.z-mu)*rs*gg.z + bb.z;
  o.w = (v.w-mu)*rs*gg.w + bb.w;
  p[tid] = o;
}

extern "C" void kernel_launch(void* const* d_in, const int* in_sizes, int n_in,
                              void* d_out, int out_size, void* d_ws, size_t ws_size,
                              hipStream_t stream)
{
  (void)in_sizes; (void)n_in; (void)out_size; (void)ws_size;
  const float* x      = (const float*)d_in[0];
  const float* W_in   = (const float*)d_in[1];
  const float* b_in   = (const float*)d_in[2];
  const float* conv_w = (const float*)d_in[3];
  const float* conv_b = (const float*)d_in[4];
  const float* W_bc   = (const float*)d_in[5];
  const float* b_bc   = (const float*)d_in[6];
  const float* W_dt   = (const float*)d_in[7];
  const float* b_dt   = (const float*)d_in[8];
  const float* A_log  = (const float*)d_in[9];
  const float* Dv     = (const float*)d_in[10];
  const float* W_out  = (const float*)d_in[11];
  const float* b_out  = (const float*)d_in[12];
  const float* ln_g   = (const float*)d_in[13];
  const float* ln_b   = (const float*)d_in[14];

  char* Wp = (char*)d_ws;
  __bf16* x_bf  = (__bf16*)(Wp + 0);          // 16,777,216
  __bf16* WinT  = (__bf16*)(Wp + 16777216);   //  4,194,304  [2048][1024]
  __bf16* WdbT  = (__bf16*)(Wp + 20971520);   //  2,359,296  [1152][1024] (dt rows 0..1023, bc 1024..1055, pad)
  __bf16* WoutT = (__bf16*)(Wp + 23330816);   //  2,097,152  [1024][1024]
  float*  xssm  = (float*) (Wp + 25427968);   // 33,554,432
  float*  gsil  = (float*) (Wp + 58982400);   // 33,554,432
  float*  xcf   = (float*) (Wp + 92536832);   // 33,554,432
  __bf16* xcb   = (__bf16*)(Wp + 126091264);  // 16,777,216
  float*  dtb   = (float*) (Wp + 142868480);  // 33,554,432
  float*  BCb   = (float*) (Wp + 176422912);  //  1,048,576
  __bf16* ybf   = (__bf16*)(Wp + 177471488);  // 16,777,216  -> total ~194.2MB

  // zero the padded rows of WdbT (N=1056 tile-guard region)
  hipMemsetAsync(WdbT, 0, (size_t)1152*1024*2, stream);

  cast_bf16_kernel<<<8192,256,0,stream>>>(x, x_bf, (M_ROWS*D_MODEL)/4);
  transpose_cast_kernel<<<dim3(64,32), dim3(32,8),0,stream>>>(W_in,  WinT,  1024, 2048);
  transpose_cast_kernel<<<dim3(32,32), dim3(32,8),0,stream>>>(W_dt,  WdbT,  1024, 1024);
  transpose_cast_kernel<<<dim3(1,32),  dim3(32,8),0,stream>>>(W_bc,  WdbT + (size_t)1024*1024, 1024, 32);
  transpose_cast_kernel<<<dim3(32,32), dim3(32,8),0,stream>>>(W_out, WoutT, 1024, 1024);

  // proj = x @ W_in + b_in ; split -> xssm, silu(gate)
  gemm_bt<0><<<dim3(16,64),256,0,stream>>>(x_bf, WinT, 2048, 1024, b_in, nullptr, xssm, gsil, nullptr);
  // causal depthwise conv + silu
  conv_silu_kernel<<<M_ROWS,256,0,stream>>>(xssm, conv_w, conv_b, xcf, xcb);
  // [dt | BC] = x_conv @ [W_dt | W_bc] ; softplus on dt
  gemm_bt<1><<<dim3(9,64),256,0,stream>>>(xcb, WdbT, 1056, 1024, b_dt, b_bc, dtb, BCb, nullptr);
  // selective scan + D-skip + gating -> y (bf16)
  scan_kernel<<<dim3(64,4),256,0,stream>>>(xcf, dtb, BCb, A_log, Dv, gsil, ybf);
  // out = y @ W_out + b_out + x  (residual)
  gemm_bt<2><<<dim3(8,64),256,0,stream>>>(ybf, WoutT, 1024, 1024, b_out, nullptr, (float*)d_out, nullptr, x);
  // layernorm in place
  ln_kernel<<<M_ROWS,256,0,stream>>>((float*)d_out, ln_g, ln_b);
}

// Round 5
// 526.381 us; speedup vs baseline: 1.5727x; 1.5727x over previous
//
#include <hip/hip_runtime.h>
#include <stdint.h>

#define D_MODEL 1024
#define T_SEQ   2048
#define N_BATCH 4
#define M_ROWS  (N_BATCH*T_SEQ)   // 8192
#define N_STATE 16
#define SEGS    16
#define SEGLEN  (T_SEQ/SEGS)      // 128

typedef float  f32x4  __attribute__((ext_vector_type(4)));
typedef __bf16 bf16x8 __attribute__((ext_vector_type(8)));
typedef __bf16 bf16x4 __attribute__((ext_vector_type(4)));

__device__ __forceinline__ void gload16(const void* g, void* l) {
  __builtin_amdgcn_global_load_lds(
      (const __attribute__((address_space(1))) uint32_t*)g,
      (__attribute__((address_space(3))) uint32_t*)l, 16, 0, 0);
}

__device__ __forceinline__ float sigmoidf_(float v){ return 1.f/(1.f+__expf(-v)); }

// ---------------- cast fp32 -> bf16 ----------------
__global__ __launch_bounds__(256) void cast_bf16_kernel(const float* __restrict__ in,
                                                        __bf16* __restrict__ out, int n4){
  int i = blockIdx.x*256 + threadIdx.x;
  if (i >= n4) return;
  float4 v = ((const float4*)in)[i];
  bf16x4 o; o[0]=(__bf16)v.x; o[1]=(__bf16)v.y; o[2]=(__bf16)v.z; o[3]=(__bf16)v.w;
  ((bf16x4*)out)[i] = o;
}

// ---------------- transpose + cast: W (K x N) fp32 -> out (N x K) bf16 ----------------
__global__ __launch_bounds__(256) void transpose_cast_kernel(const float* __restrict__ W,
                                                             __bf16* __restrict__ out,
                                                             int K, int N){
  __shared__ float tile[32][33];
  const int tx = threadIdx.x, ty = threadIdx.y;
  const int n0 = blockIdx.x*32, k0 = blockIdx.y*32;
  #pragma unroll
  for (int i=0;i<4;i++)
    tile[ty+i*8][tx] = W[(size_t)(k0+ty+i*8)*N + n0+tx];
  __syncthreads();
  #pragma unroll
  for (int i=0;i<4;i++)
    out[(size_t)(n0+ty+i*8)*K + k0+tx] = (__bf16)tile[tx][ty+i*8];
}

// ---------------- MFMA GEMM: C = A(MxK) * Bt(NxK)^T, m97-style 128x128 tile ----------------
#define BM 128
#define BN 128
#define BK 32

// EPI 0: proj -> out0b=x_ssm bf16 (col<1024), out1b=silu(gate) bf16 (col>=1024)
// EPI 1: dt/BC -> out0=softplus(v+b_dt) fp32 (col<1024), out1=BC raw fp32 (stride 32)
// EPI 2: out0 = v + bias0 + addx  (residual pre-LN, fp32)
template<int EPI>
__global__ __launch_bounds__(256)
void gemm_bt(const __bf16* __restrict__ A, const __bf16* __restrict__ Bt,
             int N, int K,
             const float* __restrict__ bias0, const float* __restrict__ bias1,
             float* __restrict__ out0, float* __restrict__ out1,
             const float* __restrict__ addx,
             __bf16* __restrict__ out0b, __bf16* __restrict__ out1b)
{
  __shared__ __align__(16) __bf16 As[BM*BK];
  __shared__ __align__(16) __bf16 Bs[BN*BK];
  const int tid = threadIdx.x, wave = tid>>6, lane = tid&63;
  const int m0 = blockIdx.y*BM, n0 = blockIdx.x*BN;
  const int wr = wave>>1, wc = wave&1;

  f32x4 acc[4][4];
  #pragma unroll
  for (int a=0;a<4;a++)
    #pragma unroll
    for (int b=0;b<4;b++) acc[a][b] = (f32x4){0.f,0.f,0.f,0.f};

  const int c0 = wave*128 + lane, c1 = c0 + 64;
  const int r0 = c0>>2, s0 = (c0&3)*8;
  const int r1 = c1>>2, s1 = (c1&3)*8;
  const int arow = wr*64 + (lane&15), brow = wc*64 + (lane&15);
  const int kg = (lane>>4)*8;

  for (int kk=0; kk<K; kk+=BK) {
    gload16(&A [(size_t)(m0+r0)*K + kk + s0], &As[c0*8]);
    gload16(&A [(size_t)(m0+r1)*K + kk + s1], &As[c1*8]);
    gload16(&Bt[(size_t)(n0+r0)*K + kk + s0], &Bs[c0*8]);
    gload16(&Bt[(size_t)(n0+r1)*K + kk + s1], &Bs[c1*8]);
    __syncthreads();
    bf16x8 af[4], bfv[4];
    #pragma unroll
    for (int m=0;m<4;m++) af[m]  = *(const bf16x8*)&As[(arow+m*16)*BK + kg];
    #pragma unroll
    for (int n=0;n<4;n++) bfv[n] = *(const bf16x8*)&Bs[(brow+n*16)*BK + kg];
    #pragma unroll
    for (int m=0;m<4;m++)
      #pragma unroll
      for (int n=0;n<4;n++)
        acc[m][n] = __builtin_amdgcn_mfma_f32_16x16x32_bf16(af[m], bfv[n], acc[m][n], 0,0,0);
    __syncthreads();
  }

  const int cr = (lane>>4)*4, cc = lane&15;
  #pragma unroll
  for (int m=0;m<4;m++){
    const int row = m0 + wr*64 + m*16 + cr;
    #pragma unroll
    for (int n=0;n<4;n++){
      const int col = n0 + wc*64 + n*16 + cc;
      if (col >= N) continue;
      #pragma unroll
      for (int r=0;r<4;r++){
        float v = acc[m][n][r];
        const size_t ri = (size_t)(row + r);
        if constexpr (EPI==0){
          v += bias0[col];
          if (col < D_MODEL) out0b[ri*D_MODEL + col] = (__bf16)v;
          else               out1b[ri*D_MODEL + (col-D_MODEL)] = (__bf16)(v * sigmoidf_(v));
        } else if constexpr (EPI==1){
          if (col < D_MODEL){
            v += bias0[col];
            out0[ri*D_MODEL + col] = (v > 20.f) ? v : log1pf(__expf(v));
          } else {
            v += bias1[col-D_MODEL];
            out1[ri*32 + (col-D_MODEL)] = v;
          }
        } else {
          v += bias0[col] + addx[ri*D_MODEL + col];
          out0[ri*D_MODEL + col] = v;
        }
      }
    }
  }
}

// ---------------- causal depthwise conv(4) + silu (bf16 in, bf16 out) ----------------
__global__ __launch_bounds__(256) void conv_silu_kernel(
    const __bf16* __restrict__ xssm, const float* __restrict__ cw, const float* __restrict__ cb,
    __bf16* __restrict__ xcb)
{
  const int bt = blockIdx.x;            // b*T + t
  const int t  = bt & (T_SEQ-1);
  const int d  = threadIdx.x*4;
  float4 w[4];
  #pragma unroll
  for (int j=0;j<4;j++) w[j] = *(const float4*)&cw[(d+j)*4];
  float4 acc = *(const float4*)&cb[d];
  #pragma unroll
  for (int k=0;k<4;k++){
    const int tt = t-3+k;
    if (tt >= 0){
      bf16x4 xv = ((const bf16x4*)xssm)[((size_t)(bt-3+k)*D_MODEL + d)>>2];
      acc.x = fmaf((float)xv[0], ((const float*)&w[0])[k], acc.x);
      acc.y = fmaf((float)xv[1], ((const float*)&w[1])[k], acc.y);
      acc.z = fmaf((float)xv[2], ((const float*)&w[2])[k], acc.z);
      acc.w = fmaf((float)xv[3], ((const float*)&w[3])[k], acc.w);
    }
  }
  acc.x *= sigmoidf_(acc.x); acc.y *= sigmoidf_(acc.y);
  acc.z *= sigmoidf_(acc.z); acc.w *= sigmoidf_(acc.w);
  bf16x4 o; o[0]=(__bf16)acc.x; o[1]=(__bf16)acc.y; o[2]=(__bf16)acc.z; o[3]=(__bf16)acc.w;
  ((bf16x4*)xcb)[((size_t)bt*D_MODEL + d)>>2] = o;
}

// ---------------- segmented selective scan ----------------
// Phase 1: per segment (h0=0): e = local end state, P = exp(a * sum_dt)
__global__ __launch_bounds__(256) void scan_p1(
    const __bf16* __restrict__ xcb, const float* __restrict__ dtb, const float* __restrict__ BC,
    const float* __restrict__ A_log, float* __restrict__ Ebuf, float* __restrict__ Pbuf)
{
  const int dg = blockIdx.x, b = blockIdx.y, sg = blockIdx.z;
  const int d0 = dg*16;
  const int tid = threadIdx.x, wave = tid>>6, lane = tid&63;
  const int n = lane & 15, dl = wave*4 + (lane>>4);
  const int d = d0 + dl;
  const float a_dn = -__expf(A_log[(size_t)d*N_STATE + n]);
  __shared__ float s_dt[16][16], s_xc[16][16], s_B[16][16];
  float h = 0.f, sdt = 0.f;
  const int lt = tid>>4, ldd = tid&15;
  const size_t baseM = (size_t)b*T_SEQ + (size_t)sg*SEGLEN;

  for (int tc=0; tc<SEGLEN; tc+=16){
    const size_t row = baseM + tc + lt;
    s_dt[lt][ldd] = dtb[row*D_MODEL + d0 + ldd];
    s_xc[lt][ldd] = (float)xcb[row*D_MODEL + d0 + ldd];
    s_B [lt][ldd] = BC[row*32 + ldd];
    __syncthreads();
    #pragma unroll
    for (int t=0;t<16;t++){
      const float dtv = s_dt[t][dl];
      const float dA = __expf(dtv * a_dn);
      h = fmaf(h, dA, dtv * s_xc[t][dl] * s_B[t][n]);
      sdt += dtv;
    }
    __syncthreads();
  }
  const size_t idx = (((size_t)sg*N_BATCH + b)*D_MODEL + d)*N_STATE + n;
  Ebuf[idx] = h;
  Pbuf[idx] = __expf(a_dn * sdt);
}

// Phase 2: carry scan across segments; Ebuf[idx] is replaced by the carry-IN for segment s
__global__ __launch_bounds__(256) void scan_p2(float* __restrict__ Ebuf,
                                               const float* __restrict__ Pbuf)
{
  const size_t g = (size_t)blockIdx.x*256 + threadIdx.x;  // 0..65535 = (b,d,n)
  float c = 0.f;
  #pragma unroll
  for (int s=0;s<SEGS;s++){
    const size_t idx = (size_t)s*(N_BATCH*D_MODEL*N_STATE) + g;
    const float e = Ebuf[idx];
    const float p = Pbuf[idx];
    Ebuf[idx] = c;
    c = fmaf(p, c, e);
  }
}

// Phase 3: full scan within segment starting from carry; emits y*silu(gate) in bf16
__global__ __launch_bounds__(256) void scan_p3(
    const __bf16* __restrict__ xcb, const float* __restrict__ dtb, const float* __restrict__ BC,
    const float* __restrict__ A_log, const float* __restrict__ Dvec,
    const __bf16* __restrict__ gsil, const float* __restrict__ Ebuf,
    __bf16* __restrict__ ybf)
{
  const int dg = blockIdx.x, b = blockIdx.y, sg = blockIdx.z;
  const int d0 = dg*16;
  const int tid = threadIdx.x, wave = tid>>6, lane = tid&63;
  const int n = lane & 15, dl = wave*4 + (lane>>4);
  const int d = d0 + dl;
  const float a_dn = -__expf(A_log[(size_t)d*N_STATE + n]);
  const float Dd = Dvec[d];
  __shared__ float s_dt[16][16], s_xc[16][16], s_B[16][16], s_C[16][16], s_y[16][16];
  float h = Ebuf[(((size_t)sg*N_BATCH + b)*D_MODEL + d)*N_STATE + n];
  const int lt = tid>>4, ldd = tid&15;
  const size_t baseM = (size_t)b*T_SEQ + (size_t)sg*SEGLEN;

  for (int tc=0; tc<SEGLEN; tc+=16){
    const size_t row = baseM + tc + lt;
    s_dt[lt][ldd] = dtb[row*D_MODEL + d0 + ldd];
    s_xc[lt][ldd] = (float)xcb[row*D_MODEL + d0 + ldd];
    s_B [lt][ldd] = BC[row*32 + ldd];
    s_C [lt][ldd] = BC[row*32 + 16 + ldd];
    __syncthreads();
    #pragma unroll
    for (int t=0;t<16;t++){
      const float dtv = s_dt[t][dl], xcv = s_xc[t][dl];
      const float dA = __expf(dtv * a_dn);
      h = fmaf(h, dA, dtv*xcv*s_B[t][n]);
      float py = h * s_C[t][n];
      py += __shfl_xor(py,1); py += __shfl_xor(py,2);
      py += __shfl_xor(py,4); py += __shfl_xor(py,8);
      if (n==0) s_y[t][dl] = fmaf(Dd, xcv, py);
    }
    __syncthreads();
    const float yv = s_y[lt][ldd] * (float)gsil[row*D_MODEL + d0 + ldd];
    ybf[row*D_MODEL + d0 + ldd] = (__bf16)yv;
  }
}

// ---------------- layernorm, in place on d_out ----------------
__global__ __launch_bounds__(256) void ln_kernel(float* __restrict__ io,
    const float* __restrict__ g, const float* __restrict__ b)
{
  const int row = blockIdx.x, tid = threadIdx.x;
  float4* p = (float4*)(io + (size_t)row*D_MODEL);
  float4 v = p[tid];
  float s  = v.x+v.y+v.z+v.w;
  float s2 = v.x*v.x + v.y*v.y + v.z*v.z + v.w*v.w;
  #pragma unroll
  for (int o=1;o<64;o<<=1){ s += __shfl_xor(s,o); s2 += __shfl_xor(s2,o); }
  __shared__ float red[8];
  const int wave = tid>>6, lane = tid&63;
  if (lane==0){ red[wave]=s; red[4+wave]=s2; }
  __syncthreads();
  s  = red[0]+red[1]+red[2]+red[3];
  s2 = red[4]+red[5]+red[6]+red[7];
  const float mu  = s*(1.f/D_MODEL);
  const float var = s2*(1.f/D_MODEL) - mu*mu;
  const float rs  = rsqrtf(var + 1e-5f);
  float4 gg = ((const float4*)g)[tid], bb = ((const float4*)b)[tid];
  float4 o;
  o.x = (v.x-mu)*rs*gg.x + bb.x;
  o.y = (v.y-mu)*rs*gg.y + bb.y;
  o.z = (v.z-mu)*rs*gg.z + bb.z;
  o.w = (v.w-mu)*rs*gg.w + bb.w;
  p[tid] = o;
}

extern "C" void kernel_launch(void* const* d_in, const int* in_sizes, int n_in,
                              void* d_out, int out_size, void* d_ws, size_t ws_size,
                              hipStream_t stream)
{
  (void)in_sizes; (void)n_in; (void)out_size; (void)ws_size;
  const float* x      = (const float*)d_in[0];
  const float* W_in   = (const float*)d_in[1];
  const float* b_in   = (const float*)d_in[2];
  const float* conv_w = (const float*)d_in[3];
  const float* conv_b = (const float*)d_in[4];
  const float* W_bc   = (const float*)d_in[5];
  const float* b_bc   = (const float*)d_in[6];
  const float* W_dt   = (const float*)d_in[7];
  const float* b_dt   = (const float*)d_in[8];
  const float* A_log  = (const float*)d_in[9];
  const float* Dv     = (const float*)d_in[10];
  const float* W_out  = (const float*)d_in[11];
  const float* b_out  = (const float*)d_in[12];
  const float* ln_g   = (const float*)d_in[13];
  const float* ln_b   = (const float*)d_in[14];

  char* Wp = (char*)d_ws;
  __bf16* x_bf    = (__bf16*)(Wp + 0);          // 16 MB
  __bf16* WinT    = (__bf16*)(Wp + 16777216);   //  4 MB  [2048][1024]
  __bf16* WdbT    = (__bf16*)(Wp + 20971520);   // 2.25MB [1152][1024]
  __bf16* WoutT   = (__bf16*)(Wp + 23330816);   //  2 MB  [1024][1024]
  __bf16* xssm_bf = (__bf16*)(Wp + 25427968);   // 16 MB (dead after conv; tail reused for E/P)
  __bf16* gsil_bf = (__bf16*)(Wp + 58982400);   // 16 MB
  __bf16* xcb     = (__bf16*)(Wp + 126091264);  // 16 MB
  float*  dtb     = (float*) (Wp + 142868480);  // 32 MB
  float*  BCb     = (float*) (Wp + 176422912);  //  1 MB
  __bf16* ybf     = (__bf16*)(Wp + 177471488);  // 16 MB

  // E/P carry buffers: 4MB each — placed in the (free) region after xssm_bf's 16MB
  float* Ebuf = (float*)(Wp + 42205184);
  float* Pbuf = (float*)(Wp + 46399488);

  hipMemsetAsync(WdbT, 0, (size_t)1152*1024*2, stream);

  cast_bf16_kernel<<<8192,256,0,stream>>>(x, x_bf, (M_ROWS*D_MODEL)/4);
  transpose_cast_kernel<<<dim3(64,32), dim3(32,8),0,stream>>>(W_in,  WinT,  1024, 2048);
  transpose_cast_kernel<<<dim3(32,32), dim3(32,8),0,stream>>>(W_dt,  WdbT,  1024, 1024);
  transpose_cast_kernel<<<dim3(1,32),  dim3(32,8),0,stream>>>(W_bc,  WdbT + (size_t)1024*1024, 1024, 32);
  transpose_cast_kernel<<<dim3(32,32), dim3(32,8),0,stream>>>(W_out, WoutT, 1024, 1024);

  // proj = x @ W_in + b_in ; -> bf16 x_ssm, bf16 silu(gate)
  gemm_bt<0><<<dim3(16,64),256,0,stream>>>(x_bf, WinT, 2048, 1024, b_in, nullptr,
                                           nullptr, nullptr, nullptr, xssm_bf, gsil_bf);
  conv_silu_kernel<<<M_ROWS,256,0,stream>>>(xssm_bf, conv_w, conv_b, xcb);
  gemm_bt<1><<<dim3(9,64),256,0,stream>>>(xcb, WdbT, 1056, 1024, b_dt, b_bc,
                                          dtb, BCb, nullptr, nullptr, nullptr);

  scan_p1<<<dim3(64,4,SEGS),256,0,stream>>>(xcb, dtb, BCb, A_log, Ebuf, Pbuf);
  scan_p2<<<256,256,0,stream>>>(Ebuf, Pbuf);
  scan_p3<<<dim3(64,4,SEGS),256,0,stream>>>(xcb, dtb, BCb, A_log, Dv, gsil_bf, Ebuf, ybf);

  gemm_bt<2><<<dim3(8,64),256,0,stream>>>(ybf, WoutT, 1024, 1024, b_out, nullptr,
                                          (float*)d_out, nullptr, x, nullptr, nullptr);
  ln_kernel<<<M_ROWS,256,0,stream>>>((float*)d_out, ln_g, ln_b);
}